// Round 4
// baseline (166.600 us; speedup 1.0000x reference)
//
#include <hip/hip_runtime.h>
#include <hip/hip_bf16.h>
#include <stdint.h>

// TypedLinear: out[i] = W[types[i]] @ x[i] + b[types[i]]
// N=65536, IN=OUT=256, T=8, fp32 in/out.
// R4: NO global sort. Each block owns 128 consecutive rows (coalesced A read,
// near-coalesced out write), groups rows by type locally in LDS, runs per-type
// 16-row MFMA groups with B served from L2 (W is 1 MB -> L2/L1 resident).
// 2 kernel launches total.

#define NROWS 65536
#define NTYPES 8
#define KDIM 256
#define ODIM 256
#define BR 128          // rows per block

typedef __attribute__((ext_vector_type(8))) short short8;
typedef __attribute__((ext_vector_type(4))) float f32x4;

__device__ __forceinline__ unsigned short f2bf(float f) {
    unsigned int u = __float_as_uint(f);
    u += 0x7fffu + ((u >> 16) & 1u);   // RNE
    return (unsigned short)(u >> 16);
}

// ---- K1: W fp32 -> bf16 (1 MB, L2-resident afterwards) ----
__global__ void prep_kernel(const float* __restrict__ W,
                            unsigned short* __restrict__ Wb) {
    #pragma unroll
    for (int r = 0; r < 2; ++r) {
        int j = blockIdx.x * 512 + r * 256 + threadIdx.x;
        float4 v = ((const float4*)W)[j];
        ushort4 p;
        p.x = f2bf(v.x); p.y = f2bf(v.y); p.z = f2bf(v.z); p.w = f2bf(v.w);
        ((ushort4*)Wb)[j] = p;
    }
}

// ---- K2: fused typed-linear. 512 blocks x 512 thr (8 waves, 32 N-cols each).
// LDS: A full-K bf16 [128][256], 16B-chunk XOR swizzle; local type grouping.
__global__ __launch_bounds__(512, 4)
void typed_linear_kernel(const float* __restrict__ x,
                         const int* __restrict__ types,
                         const float* __restrict__ bias,
                         const unsigned short* __restrict__ Wb,
                         float* __restrict__ out) {
    __shared__ unsigned short As[BR * KDIM];   // 64 KB
    __shared__ int rlist[BR];
    __shared__ int tcnt[NTYPES], tstart[NTYPES], tcur[NTYPES];

    const int tid = threadIdx.x;
    const int wave = tid >> 6;
    const int lane = tid & 63;
    const int lr = lane & 15;
    const int lq = lane >> 4;
    const int wn = wave * 32;                  // this wave's 32-col N slice
    const int row0 = blockIdx.x * BR;
    char* AsB = (char*)As;

    // --- local grouping by type (before big loads: barriers here are cheap) ---
    if (tid < NTYPES) tcnt[tid] = 0;
    __syncthreads();
    int myt = 0;
    if (tid < BR) {
        myt = types[row0 + tid];
        atomicAdd(&tcnt[myt], 1);              // LDS atomic
    }
    __syncthreads();
    if (tid == 0) {
        int acc = 0;
        #pragma unroll
        for (int t = 0; t < NTYPES; ++t) { tstart[t] = acc; tcur[t] = acc; acc += tcnt[t]; }
    }
    __syncthreads();
    if (tid < BR) {
        int p = atomicAdd(&tcur[myt], 1);      // LDS atomic
        rlist[p] = tid;
    }
    // (rlist published by the barrier after the A-stage below)

    // --- bias preload: 16 regs/lane, L2-hot ---
    float breg[NTYPES][2];
    #pragma unroll
    for (int t = 0; t < NTYPES; ++t)
        #pragma unroll
        for (int f = 0; f < 2; ++f)
            breg[t][f] = bias[t * ODIM + wn + f * 16 + lr];

    // --- stage A: 128 rows x 256 fp32, fully coalesced -> bf16 LDS, swizzled ---
    float4 av[16];
    const float4* xb = (const float4*)(x + (size_t)row0 * KDIM);
    #pragma unroll
    for (int i = 0; i < 16; ++i) av[i] = xb[tid + i * 512];
    #pragma unroll
    for (int i = 0; i < 16; ++i) {
        int flat = tid + i * 512;
        int row = flat >> 6, c4 = flat & 63;   // c4: float4 slot in the 1 KB row
        ushort4 p;
        p.x = f2bf(av[i].x); p.y = f2bf(av[i].y); p.z = f2bf(av[i].z); p.w = f2bf(av[i].w);
        int ch = (c4 >> 1) ^ (row & 7);        // 16B-chunk XOR swizzle
        *(ushort4*)(AsB + row * 512 + ch * 16 + (c4 & 1) * 8) = p;
    }
    __syncthreads();

    // --- per-type 16-row MFMA groups; B straight from L2 (Wb is L2-resident) ---
    const size_t wb_lane = (size_t)(wn + lr) * KDIM + lq * 8;   // element offset
    #pragma unroll
    for (int t = 0; t < NTYPES; ++t) {
        const int cnt = tcnt[t];
        if (cnt == 0) continue;
        const int st = tstart[t];
        const int ng = (cnt + 15) >> 4;
        const unsigned short* bt = Wb + (size_t)t * (ODIM * KDIM) + wb_lane;
        for (int g = 0; g < ng; ++g) {
            // A-frag row for this lane (clamped duplicate for padded slots)
            int slotA = g * 16 + lr;
            int rA = rlist[st + (slotA < cnt ? slotA : cnt - 1)];
            int abase = rA * 512;
            int asw = rA & 7;

            // issue all 16 B loads (2 N-frags x 8 K-chunks), independent
            short8 bf[2][8];
            #pragma unroll
            for (int f = 0; f < 2; ++f)
                #pragma unroll
                for (int kc = 0; kc < 8; ++kc)
                    bf[f][kc] = *(const short8*)(bt + f * 16 * KDIM + kc * 32);

            f32x4 acc0 = {}, acc1 = {};
            #pragma unroll
            for (int kc = 0; kc < 8; ++kc) {
                short8 af = *(const short8*)(AsB + abase + ((((kc << 2) + lq) ^ asw) << 4));
                acc0 = __builtin_amdgcn_mfma_f32_16x16x32_bf16(af, bf[0][kc], acc0, 0, 0, 0);
                acc1 = __builtin_amdgcn_mfma_f32_16x16x32_bf16(af, bf[1][kc], acc1, 0, 0, 0);
            }

            // epilogue: D col=lane&15, row=lq*4+reg; rows land in this block's
            // hot 128-row window -> L2 write-combines the 64 B segments
            #pragma unroll
            for (int r = 0; r < 4; ++r) {
                int slot = g * 16 + lq * 4 + r;
                if (slot < cnt) {
                    int orow = row0 + rlist[st + slot];
                    float* op = out + (size_t)orow * ODIM + wn;
                    op[lr]      = acc0[r] + breg[t][0];
                    op[16 + lr] = acc1[r] + breg[t][1];
                }
            }
        }
    }
}

extern "C" void kernel_launch(void* const* d_in, const int* in_sizes, int n_in,
                              void* d_out, int out_size, void* d_ws, size_t ws_size,
                              hipStream_t stream) {
    const float* x     = (const float*)d_in[0];
    const int*   types = (const int*)d_in[1];
    const float* W     = (const float*)d_in[2];
    const float* b     = (const float*)d_in[3];
    float* out = (float*)d_out;

    unsigned short* Wb = (unsigned short*)d_ws;   // 1 MB bf16 W

    prep_kernel<<<256, 256, 0, stream>>>(W, Wb);
    typed_linear_kernel<<<NROWS / BR, 512, 0, stream>>>(x, types, b, Wb, out);
}

// Round 5
// 157.472 us; speedup vs baseline: 1.0580x; 1.0580x over previous
//
#include <hip/hip_runtime.h>
#include <hip/hip_bf16.h>
#include <stdint.h>

// TypedLinear: out[i] = W[types[i]] @ x[i] + b[types[i]]
// N=65536, IN=OUT=256, T=8, fp32 in/out.
// R5: physically permute x into type-sorted bf16 xs (all-coalesced copy), then
// textbook GEMM with BOTH operands via global_load_lds from contiguous memory.
// 4 blocks/CU, conflict-free swizzle, contiguous 512B out-row writes.

#define NROWS 65536
#define NTYPES 8
#define KDIM 256
#define ODIM 256
#define BM 128
#define BN 128
#define BK 64
#define HB 256         // hist/permute blocks (x256 threads, 256 rows each)
#define MAXTILES 544   // >= sum ceil(cnt[t]/128) worst case (~519)

typedef __attribute__((ext_vector_type(8))) short short8;
typedef __attribute__((ext_vector_type(4))) float f32x4;

__device__ __forceinline__ unsigned short f2bf(float f) {
    unsigned int u = __float_as_uint(f);
    u += 0x7fffu + ((u >> 16) & 1u);   // RNE
    return (unsigned short)(u >> 16);
}

// ---- K1: per-block type histogram + W fp32->bf16 (fused) ----
__global__ void hist_kernel(const int* __restrict__ types,
                            const float* __restrict__ W,
                            unsigned short* __restrict__ Wb,
                            int* __restrict__ blockHist) {
    __shared__ int h[NTYPES];
    const int tid = threadIdx.x;
    if (tid < NTYPES) h[tid] = 0;
    __syncthreads();
    atomicAdd(&h[types[blockIdx.x * 256 + tid]], 1);   // LDS atomic
    #pragma unroll
    for (int r = 0; r < 2; ++r) {
        int j = blockIdx.x * 512 + r * 256 + tid;
        float4 v = ((const float4*)W)[j];
        ushort4 p;
        p.x = f2bf(v.x); p.y = f2bf(v.y); p.z = f2bf(v.z); p.w = f2bf(v.w);
        ((ushort4*)Wb)[j] = p;
    }
    __syncthreads();
    if (tid < NTYPES) blockHist[blockIdx.x * NTYPES + tid] = h[tid];
}

// ---- K2: scan + tile list (1 block x 256 thr, LDS-resident) ----
__global__ void scan_kernel(const int* __restrict__ blockHist,
                            int* __restrict__ blockBase,
                            int* __restrict__ typeBase,
                            int4* __restrict__ tiles,
                            int* __restrict__ tileCount) {
    __shared__ int v[HB * NTYPES];          // 8 KB
    __shared__ int scnt[NTYPES];
    __shared__ int sTypeBase[NTYPES], sTileBase[NTYPES + 1];
    const int tid = threadIdx.x;
    for (int j = tid; j < HB * NTYPES; j += 256) v[j] = blockHist[j];
    __syncthreads();

    const int t = tid >> 5;
    const int l = tid & 31;
    int s[8];
    int sum = 0;
    #pragma unroll
    for (int m = 0; m < 8; ++m) {
        s[m] = sum;
        sum += v[(l * 8 + m) * NTYPES + t];
    }
    int incl = sum;
    #pragma unroll
    for (int d = 1; d < 32; d <<= 1) {
        int y = __shfl_up(incl, d, 32);
        if (l >= d) incl += y;
    }
    const int excl = incl - sum;
    #pragma unroll
    for (int m = 0; m < 8; ++m)
        blockBase[(l * 8 + m) * NTYPES + t] = excl + s[m];
    if (l == 31) scnt[t] = incl;
    __syncthreads();

    if (tid == 0) {
        int rowacc = 0, tileacc = 0;
        for (int q = 0; q < NTYPES; ++q) {
            sTypeBase[q] = rowacc; typeBase[q] = rowacc; rowacc += scnt[q];
            sTileBase[q] = tileacc; tileacc += (scnt[q] + BM - 1) / BM;
        }
        sTileBase[NTYPES] = tileacc;
        tileCount[0] = tileacc;
    }
    __syncthreads();
    const int tc = sTileBase[NTYPES];
    for (int j = tid; j < tc; j += 256) {
        int q = 0;
        while (q < NTYPES - 1 && j >= sTileBase[q + 1]) ++q;
        tiles[j] = make_int4(q, (j - sTileBase[q]) * BM, sTypeBase[q], scnt[q]);
    }
}

// ---- K3: permute x into sorted bf16 xs + emit slot->orig idx ----
// 256 blocks x 256 thr. Reads fully coalesced (1 KB/row), writes 512 B/row.
__global__ void permute_kernel(const float* __restrict__ x,
                               const int* __restrict__ types,
                               const int* __restrict__ blockBase,
                               const int* __restrict__ typeBase,
                               int* __restrict__ idx,
                               unsigned short* __restrict__ xs) {
    __shared__ int h[NTYPES], base[NTYPES];
    __shared__ int slot_s[256];
    const int tid = threadIdx.x;
    if (tid < NTYPES) {
        h[tid] = 0;
        base[tid] = typeBase[tid] + blockBase[blockIdx.x * NTYPES + tid];
    }
    __syncthreads();
    const int row = blockIdx.x * 256 + tid;
    const int t = types[row];
    int r = atomicAdd(&h[t], 1);            // LDS atomic
    int slot = base[t] + r;
    slot_s[tid] = slot;
    idx[slot] = row;
    __syncthreads();

    // copy: 4 row-groups x 64 lanes; each iteration streams 4 full rows
    const int g = tid >> 6;
    const int l = tid & 63;
    const size_t r0 = (size_t)blockIdx.x * 256;
    #pragma unroll 4
    for (int m = 0; m < 64; ++m) {
        int i = g * 64 + m;
        float4 v = *(const float4*)(x + (r0 + i) * KDIM + l * 4);
        ushort4 p;
        p.x = f2bf(v.x); p.y = f2bf(v.y); p.z = f2bf(v.z); p.w = f2bf(v.w);
        *(ushort4*)(xs + (size_t)slot_s[i] * KDIM + l * 4) = p;
    }
}

// ---- K4: GEMM on sorted contiguous rows. 256 thr = 4 waves (2x2 of 64x64).
// A and B both via global_load_lds w16; 32 KB LDS -> 4 blocks/CU.
__global__ __launch_bounds__(256, 4)
void gemm_kernel(const unsigned short* __restrict__ xs,
                 const float* __restrict__ bias,
                 const unsigned short* __restrict__ Wb,
                 const int* __restrict__ tileCount,
                 const int4* __restrict__ tiles,
                 const int* __restrict__ idx,
                 float* __restrict__ out) {
    if ((int)blockIdx.x >= tileCount[0]) return;   // uniform, pre-barrier
    const int4 td = tiles[blockIdx.x];
    const int t = td.x, m0 = td.y, rbase = td.z, count = td.w;
    const int n0 = blockIdx.y * BN;
    const int rem = count - m0;                    // >= 1

    __shared__ unsigned short As[BM * BK];         // 16 KB, swizzled
    __shared__ unsigned short Bs[BN * BK];         // 16 KB, swizzled

    const int tid = threadIdx.x;
    const int wave = tid >> 6;
    const int lane = tid & 63;
    const int lr = lane & 15;
    const int lq = lane >> 4;
    const int wm = (wave >> 1) * 64;
    const int wn = (wave & 1) * 64;

    // glds staging: dest = uniform base + lane*16 -> row = ..+(lane>>3), chunk = lane&7
    const int schunk = (lane & 7) ^ ((lane >> 3) & 7);   // source chunk (XOR swizzle)
    const unsigned short* asrc0 = xs + (size_t)(rbase + m0) * KDIM + (size_t)schunk * 8;
    const unsigned short* bsrc0 = Wb + ((size_t)t * ODIM + n0) * KDIM + (size_t)schunk * 8;

    float breg[4];
    #pragma unroll
    for (int j = 0; j < 4; ++j) breg[j] = bias[t * ODIM + n0 + wn + j * 16 + lr];

    f32x4 acc[4][4] = {};
    char* AsB = (char*)As;
    char* BsB = (char*)Bs;

    for (int k0 = 0; k0 < KDIM; k0 += BK) {
        #pragma unroll
        for (int issue = 0; issue < 4; ++issue) {
            int dbyte = issue * 4096 + wave * 1024;        // wave-uniform
            int row = issue * 32 + wave * 8 + (lane >> 3);
            __builtin_amdgcn_global_load_lds(
                (const __attribute__((address_space(1))) void*)(asrc0 + (size_t)row * KDIM + k0),
                (__attribute__((address_space(3))) void*)(AsB + dbyte), 16, 0, 0);
            __builtin_amdgcn_global_load_lds(
                (const __attribute__((address_space(1))) void*)(bsrc0 + (size_t)row * KDIM + k0),
                (__attribute__((address_space(3))) void*)(BsB + dbyte), 16, 0, 0);
        }
        __syncthreads();   // drains glds + publishes

        #pragma unroll
        for (int kh = 0; kh < 2; ++kh) {
            short8 af[4], bfr[4];
            #pragma unroll
            for (int q = 0; q < 4; ++q) {
                int arow = wm + q * 16 + lr;
                int ach = ((kh << 2) + lq) ^ (arow & 7);
                af[q] = *(const short8*)(AsB + arow * 128 + ach * 16);
            }
            #pragma unroll
            for (int q = 0; q < 4; ++q) {
                int brow = wn + q * 16 + lr;
                int bch = ((kh << 2) + lq) ^ (brow & 7);
                bfr[q] = *(const short8*)(BsB + brow * 128 + bch * 16);
            }
            #pragma unroll
            for (int q = 0; q < 4; ++q)
                #pragma unroll
                for (int j = 0; j < 4; ++j)
                    acc[q][j] = __builtin_amdgcn_mfma_f32_16x16x32_bf16(
                        af[q], bfr[j], acc[q][j], 0, 0, 0);
        }
        __syncthreads();
    }

    // epilogue: D col=lane&15, row=(lane>>4)*4+reg; out rows = 512B contiguous
    const int* rowIdx = idx + rbase + m0;
    #pragma unroll
    for (int q = 0; q < 4; ++q) {
        #pragma unroll
        for (int r = 0; r < 4; ++r) {
            int lm = wm + q * 16 + lq * 4 + r;
            if (lm < rem) {
                size_t orow = (size_t)rowIdx[lm] * ODIM;
                #pragma unroll
                for (int j = 0; j < 4; ++j)
                    out[orow + n0 + wn + j * 16 + lr] = acc[q][j][r] + breg[j];
            }
        }
    }
}

extern "C" void kernel_launch(void* const* d_in, const int* in_sizes, int n_in,
                              void* d_out, int out_size, void* d_ws, size_t ws_size,
                              hipStream_t stream) {
    const float* x     = (const float*)d_in[0];
    const int*   types = (const int*)d_in[1];
    const float* W     = (const float*)d_in[2];
    const float* b     = (const float*)d_in[3];
    float* out = (float*)d_out;

    // ws layout (bytes):
    //       0: tileCount
    //     128: typeBase[8]
    //     512: blockHist[256*8]   (8 KB)
    //    8704: blockBase[256*8]   (8 KB)
    //   16896: tiles[544] int4    (8.5 KB)
    //   25600: idx[65536]         (256 KB)
    //  287744: Wb bf16[8*256*256] (1 MB)
    // 1336320: xs bf16[65536*256] (32 MB) + 64 KB OOB pad   -> ~35 MB total
    char* ws = (char*)d_ws;
    int*  tileCount = (int*)ws;
    int*  typeBase  = (int*)(ws + 128);
    int*  blockHist = (int*)(ws + 512);
    int*  blockBase = (int*)(ws + 8704);
    int4* tiles     = (int4*)(ws + 16896);
    int*  idx       = (int*)(ws + 25600);
    unsigned short* Wb = (unsigned short*)(ws + 287744);
    unsigned short* xs = (unsigned short*)(ws + 1336320);

    hist_kernel<<<HB, 256, 0, stream>>>(types, W, Wb, blockHist);
    scan_kernel<<<1, 256, 0, stream>>>(blockHist, blockBase, typeBase, tiles, tileCount);
    permute_kernel<<<HB, 256, 0, stream>>>(x, types, blockBase, typeBase, idx, xs);
    gemm_kernel<<<dim3(MAXTILES, 2), 256, 0, stream>>>(xs, b, Wb, tileCount, tiles, idx, out);
}